// Round 5
// baseline (444.593 us; speedup 1.0000x reference)
//
#include <hip/hip_runtime.h>
#include <hip/hip_bf16.h>

// Head attention: B=16, T=2048, C=512(n_embd), H=64(head)
// out[b,t,h] = softmax_causal( (x@Wq)(x@Wk)^T * C^-0.5 ) @ (x@Wv)
// FUSED persistent kernel: phase0 (W^T + end-scan) -> barrier ->
// phaseA (qkv projections) -> barrier -> phaseB (flash attention).
// Grid 1024 = 256 CU x 4 blocks (co-resident: launch_bounds(256,4) caps
// VGPR at 128, LDS 32KB <= 40KB/block) so the spin barrier cannot deadlock.

#define B_ 16
#define T_ 2048
#define C_ 512

typedef __attribute__((ext_vector_type(4))) float f32x4;
typedef __attribute__((ext_vector_type(8))) short bf16x8;
typedef __attribute__((ext_vector_type(4))) short bf16x4;

__device__ inline unsigned short f2bf(float f) {
    unsigned int u = __builtin_bit_cast(unsigned int, f);
    u += 0x7fff + ((u >> 16) & 1);   // RNE
    return (unsigned short)(u >> 16);
}

__device__ inline f32x4 mfma16(bf16x8 a, bf16x8 b, f32x4 c) {
    return __builtin_amdgcn_mfma_f32_16x16x32_bf16(a, b, c, 0, 0, 0);
}

__device__ inline void grid_barrier(int* bar, int target) {
    __syncthreads();
    if (threadIdx.x == 0) {
        __hip_atomic_fetch_add(bar, 1, __ATOMIC_RELEASE, __HIP_MEMORY_SCOPE_AGENT);
        while (__hip_atomic_load(bar, __ATOMIC_ACQUIRE, __HIP_MEMORY_SCOPE_AGENT) < target)
            __builtin_amdgcn_s_sleep(2);
    }
    __syncthreads();
}

__global__ __launch_bounds__(256, 4) void fused_kernel(
        const float* __restrict__ x, const float* __restrict__ Wk,
        const float* __restrict__ Wq, const float* __restrict__ Wv,
        const int* __restrict__ idx, unsigned short* __restrict__ Wt,
        unsigned short* __restrict__ Qm, unsigned short* __restrict__ Km,
        unsigned short* __restrict__ Vt, int* __restrict__ fe,
        int* __restrict__ bar, float* __restrict__ out) {
    __shared__ __align__(16) char smem[32768];
    int bx = blockIdx.x, tid = threadIdx.x;
    int wave = tid >> 6, lane = tid & 63;
    int m16 = lane & 15, quad = lane >> 4;

    // ================= phase 0: W transpose (+scale) & end-token scan =======
    if (bx < 384) {
        int id = bx * 256 + tid;                 // [0, 3*32768)
        int mtx = id >> 15, rem = id & 32767;
        int k = rem >> 6, nl = rem & 63;
        const float* W = (mtx == 0) ? Wk : ((mtx == 1) ? Wq : Wv);
        float v = W[rem];                        // coalesced read
        if (mtx == 1) v *= 0.04419417382415922f * 1.4426950408889634f; // /sqrt(512)*log2e
        Wt[(mtx * 64 + nl) * 512 + k] = f2bf(v);
    } else if (bx < 416) {
        int base = (bx - 384) * 1024;
#pragma unroll
        for (int i = 0; i < 4; i++) {
            int j = base + i * 256 + tid;
            if (idx[j] == 32000) atomicMin(&fe[j >> 11], j & 2047);
        }
    }
    grid_barrier(bar, 1024);

    // ================= phase A: qkv projection, 32 tokens/block =============
    {
        unsigned short* xs = (unsigned short*)smem;       // [32][512] swizzled
        int row0 = bx * 32;
#pragma unroll
        for (int i = 0; i < 8; i++) {            // stage x tile (coalesced)
            int u = tid + i * 256;               // 2048 units of 8 floats
            int row = u >> 6, cu = u & 63;
            const f32x4* p = (const f32x4*)(x + (long)(row0 + row) * C_ + cu * 8);
            f32x4 a = p[0], bq = p[1];
            bf16x8 t;
#pragma unroll
            for (int j = 0; j < 4; j++) { t[j] = (short)f2bf(a[j]); t[4 + j] = (short)f2bf(bq[j]); }
            *(bf16x8*)&xs[row * 512 + ((cu ^ (row & 7)) * 8)] = t;
        }
        __syncthreads();

        f32x4 ka[2], qa[2], va[2];
#pragma unroll
        for (int i = 0; i < 2; i++) {
            ka[i] = (f32x4){0.f, 0.f, 0.f, 0.f};
            qa[i] = (f32x4){0.f, 0.f, 0.f, 0.f};
            va[i] = (f32x4){0.f, 0.f, 0.f, 0.f};
        }
        int krw = (wave * 16 + m16) * 512;
        int qrw = krw + 64 * 512;
        int vrw = krw + 128 * 512;

#pragma unroll 2
        for (int cb = 0; cb < 8; cb++) {
#pragma unroll
            for (int half = 0; half < 2; half++) {
                int kk = cb * 64 + half * 32 + quad * 8;
                bf16x8 wk = *(const bf16x8*)&Wt[krw + kk];
                bf16x8 wq = *(const bf16x8*)&Wt[qrw + kk];
                bf16x8 wv = *(const bf16x8*)&Wt[vrw + kk];
                int g = kk >> 3;
                bf16x8 xf[2];
#pragma unroll
                for (int mt = 0; mt < 2; mt++) {
                    int row = mt * 16 + m16;
                    xf[mt] = *(const bf16x8*)&xs[row * 512 + ((g ^ (row & 7)) * 8)];
                }
#pragma unroll
                for (int mt = 0; mt < 2; mt++) ka[mt] = mfma16(xf[mt], wk, ka[mt]);
#pragma unroll
                for (int mt = 0; mt < 2; mt++) qa[mt] = mfma16(xf[mt], wq, qa[mt]);
#pragma unroll
                for (int mt = 0; mt < 2; mt++) va[mt] = mfma16(wv, xf[mt], va[mt]); // V^T
            }
        }
        __syncthreads();                         // xs reads done -> reuse LDS

        unsigned short* co  = xs;                // [32][136] K|Q
        unsigned short* vco = xs + 32 * 136;     // [4][16][40] V^T per wave
#pragma unroll
        for (int mt = 0; mt < 2; mt++) {
#pragma unroll
            for (int r = 0; r < 4; r++) {
                int trow = mt * 16 + quad * 4 + r;
                co[trow * 136 + wave * 16 + m16]      = f2bf(ka[mt][r]);
                co[trow * 136 + 64 + wave * 16 + m16] = f2bf(qa[mt][r]);
                // va: row(feat)=quad*4+r, col(tok)=mt*16+m16
                vco[wave * 640 + (quad * 4 + r) * 40 + mt * 16 + m16] = f2bf(va[mt][r]);
            }
        }
        __syncthreads();
#pragma unroll
        for (int i = 0; i < 2; i++) {            // K/Q coalesced b128 stores
            int u = tid + i * 256; int tok = u >> 4; int fg = u & 15;
            bf16x8 vv = *(const bf16x8*)&co[tok * 136 + fg * 8];
            unsigned short* dst = (fg < 8) ? Km : Qm;
            *(bf16x8*)&dst[(long)(row0 + tok) * 64 + (fg & 7) * 8] = vv;
        }
        {                                        // V^T b128 stores
            int fl = lane >> 2, tg = lane & 3;
            bf16x8 vv = *(const bf16x8*)&vco[wave * 640 + fl * 40 + tg * 8];
            int bb = row0 >> 11, tl = row0 & 2047;
            *(bf16x8*)&Vt[((long)bb * 64 + wave * 16 + fl) * T_ + tl + tg * 8] = vv;
        }
    }
    grid_barrier(bar, 2048);

    // ================= phase B: flash attention (S^T, split-K pairs) ========
    {
        unsigned short* Plds = (unsigned short*)smem;     // [4][16*64] swizzled
        float* MO = (float*)(smem + 8192);                // [2][64*16]
        float* ML = (float*)(smem + 16384);               // [2][2][16]

        int b = bx & 15;                         // XCD = bx%8 -> b%8 locality
        int y = bx >> 4;                         // [0,64)
        int pair = wave >> 1, waveH = wave & 1;
        int qt16 = pair ? y : (127 - y);         // paired big+small q-tiles
        int qrow0 = qt16 << 4;
        long bT = (long)b * T_;

        int nfull = qt16 >> 2;                   // diagonal tile index
        int ntiles = nfull + 1;
        int half = ntiles >> 1;
        int lo = waveH ? half : 0;
        int hi = waveH ? ntiles : half;

        const unsigned short* qp = Qm + (bT + qrow0 + m16) * 64;
        bf16x8 qf0 = *(const bf16x8*)(qp + quad * 8);     // B-frag of Q^T
        bf16x8 qf1 = *(const bf16x8*)(qp + 32 + quad * 8);

        const unsigned short* Kbase = Km + bT * 64;
        const unsigned short* Vbase = Vt + (long)b * 64 * T_;

        f32x4 o[5];
#pragma unroll
        for (int h = 0; h < 5; h++) o[h] = (f32x4){0.f, 0.f, 0.f, 0.f};
        float mi = -INFINITY;                    // per-lane: q = m16
        int q_abs = qrow0 + m16;

        bf16x8 onesa;                            // all-ones A-frag (denominator)
#pragma unroll
        for (int j = 0; j < 8; j++) onesa[j] = (short)0x3F80;

        unsigned short* pw = Plds + wave * 1024;
        int msw = (m16 & 7) * 8;                 // P xor-swizzle for this lane

        for (int kt = lo; kt < hi; kt++) {
            bf16x8 kf[8];                        // K A-frags
#pragma unroll
            for (int ns = 0; ns < 4; ns++)
#pragma unroll
                for (int h = 0; h < 2; h++)
                    kf[ns * 2 + h] = *(const bf16x8*)
                        &Kbase[(kt * 64 + ns * 16 + m16) * 64 + h * 32 + quad * 8];

            bf16x8 vf[8];                        // V^T A-frags (latency overlaps QK+softmax)
#pragma unroll
            for (int hs = 0; hs < 4; hs++)
#pragma unroll
                for (int h = 0; h < 2; h++)
                    vf[hs * 2 + h] = *(const bf16x8*)
                        &Vbase[(hs * 16 + m16) * T_ + kt * 64 + h * 32 + quad * 8];

            f32x4 s[4];                          // S^T: row=key, col=q=m16
#pragma unroll
            for (int ns = 0; ns < 4; ns++) {
                f32x4 z = (f32x4){0.f, 0.f, 0.f, 0.f};
                z = mfma16(kf[ns * 2], qf0, z);
                z = mfma16(kf[ns * 2 + 1], qf1, z);
                s[ns] = z;
            }

            if (kt == nfull) {                   // causal mask on diagonal tile
#pragma unroll
                for (int ns = 0; ns < 4; ns++) {
                    int kb = kt * 64 + ns * 16 + quad * 4;
#pragma unroll
                    for (int r = 0; r < 4; r++)
                        if (kb + r > q_abs) s[ns][r] = -INFINITY;
                }
            }

            // per-lane softmax over 16 keys (scores in log2 domain)
            f32x4 t01, t;
#pragma unroll
            for (int r = 0; r < 4; r++) t01[r] = fmaxf(s[0][r], s[1][r]);
#pragma unroll
            for (int r = 0; r < 4; r++) t[r] = fmaxf(t01[r], fmaxf(s[2][r], s[3][r]));
            float mx = fmaxf(fmaxf(t[0], t[1]), fmaxf(t[2], t[3]));
            mx = fmaxf(mx, __shfl_xor(mx, 16));
            mx = fmaxf(mx, __shfl_xor(mx, 32));
            mx = fmaxf(mx, mi);
            float alpha = exp2f(mi - mx);
            mi = mx;
#pragma unroll
            for (int ns = 0; ns < 4; ns++)
#pragma unroll
                for (int r = 0; r < 4; r++) s[ns][r] = exp2f(s[ns][r] - mx);
#pragma unroll
            for (int h = 0; h < 5; h++) o[h] *= alpha;

            // P^T -> LDS [q=m16][key], xor-swizzled stride 64 (2-way = free)
#pragma unroll
            for (int ns = 0; ns < 4; ns++) {
                bf16x4 pk;
#pragma unroll
                for (int r = 0; r < 4; r++) pk[r] = (short)f2bf(s[ns][r]);
                *(bf16x4*)&pw[m16 * 64 + ((ns * 16 + quad * 4) ^ msw)] = pk;
            }
            bf16x8 pb0 = *(const bf16x8*)&pw[m16 * 64 + ((quad * 8) ^ msw)];
            bf16x8 pb1 = *(const bf16x8*)&pw[m16 * 64 + ((32 + quad * 8) ^ msw)];

#pragma unroll
            for (int hs = 0; hs < 4; hs++) {     // O^T += V^T P^T
                o[hs] = mfma16(vf[hs * 2], pb0, o[hs]);
                o[hs] = mfma16(vf[hs * 2 + 1], pb1, o[hs]);
            }
            o[4] = mfma16(onesa, pb0, o[4]);     // denominator (all lanes)
            o[4] = mfma16(onesa, pb1, o[4]);
        }

        if (!waveH) {                            // publish partial
#pragma unroll
            for (int hs = 0; hs < 4; hs++)
#pragma unroll
                for (int r = 0; r < 4; r++)
                    MO[pair * 1024 + (hs * 16 + quad * 4 + r) * 16 + m16] = o[hs][r];
            if (quad == 0) { ML[pair * 32 + m16] = mi; ML[pair * 32 + 16 + m16] = o[4][0]; }
        }
        __syncthreads();
        if (waveH) {                             // merge + store
            float m0 = ML[pair * 32 + m16], l0 = ML[pair * 32 + 16 + m16];
            float M = fmaxf(m0, mi);
            float a0 = exp2f(m0 - M);
            float a1 = exp2f(mi - M);
            float l = a0 * l0 + a1 * o[4][0];
            float inv = 1.0f / l;
            int t = qrow0 + m16;
            bool dead = (t >= fe[b]);
#pragma unroll
            for (int hs = 0; hs < 4; hs++) {
                f32x4 res;
#pragma unroll
                for (int r = 0; r < 4; r++) {
                    float v = (a1 * o[hs][r] +
                               a0 * MO[pair * 1024 + (hs * 16 + quad * 4 + r) * 16 + m16]) * inv;
                    res[r] = dead ? __builtin_nanf("") : v;
                }
                *(f32x4*)&out[(bT + t) * 64 + hs * 16 + quad * 4] = res;
            }
        }
    }
}

// ---------------------------------------------------------------------------
extern "C" void kernel_launch(void* const* d_in, const int* in_sizes, int n_in,
                              void* d_out, int out_size, void* d_ws, size_t ws_size,
                              hipStream_t stream) {
    const float* x  = (const float*)d_in[0];
    const float* Wk = (const float*)d_in[1];
    const float* Wq = (const float*)d_in[2];
    const float* Wv = (const float*)d_in[3];
    const int* idx  = (const int*)d_in[4];
    float* out = (float*)d_out;

    char* ws = (char*)d_ws;
    int* bar           = (int*)ws;                                 //     4 B
    int* fe            = (int*)(ws + 64);                          //    64 B
    unsigned short* Wt = (unsigned short*)(ws + 1024);             //  192 KiB
    unsigned short* Qm = (unsigned short*)(ws + 262144);           //    4 MiB
    unsigned short* Km = (unsigned short*)(ws + 262144 + 4194304); //    4 MiB
    unsigned short* Vt = (unsigned short*)(ws + 262144 + 8388608); //    4 MiB

    hipMemsetAsync(bar, 0, 4, stream);           // barrier counter = 0
    hipMemsetAsync(fe, 0x7F, 64, stream);        // fe init > 2047
    fused_kernel<<<1024, 256, 0, stream>>>(x, Wk, Wq, Wv, idx, Wt, Qm, Km, Vt,
                                           fe, bar, out);
}

// Round 6
// 223.403 us; speedup vs baseline: 1.9901x; 1.9901x over previous
//
#include <hip/hip_runtime.h>
#include <hip/hip_bf16.h>

// Head attention: B=16, T=2048, C=512(n_embd), H=64(head)
// out[b,t,h] = softmax_causal( (x@Wq)(x@Wk)^T * C^-0.5 ) @ (x@Wv)
// R6: un-fused (R5 spin-barrier convoy failure). 3 dispatches:
//   prep (W^T + fe init/scan) -> qkv (32 tok/block, 4 blocks/CU) ->
//   attn (S^T split-K, R4 structure + K-prefetch + packed bf16 cvt).

#define B_ 16
#define T_ 2048
#define C_ 512

typedef __attribute__((ext_vector_type(4))) float f32x4;
typedef __attribute__((ext_vector_type(8))) short bf16x8;
typedef __attribute__((ext_vector_type(4))) short bf16x4;
typedef __attribute__((ext_vector_type(4))) unsigned int u32x4;
typedef __attribute__((ext_vector_type(2))) unsigned int u32x2;

__device__ inline unsigned short f2bf(float f) {
    unsigned int u = __builtin_bit_cast(unsigned int, f);
    u += 0x7fff + ((u >> 16) & 1);   // RNE
    return (unsigned short)(u >> 16);
}

// packed f32x2 -> bf16x2 (RNE). gfx950 has v_cvt_pk_bf16_f32.
__device__ inline unsigned int f2bf_pk(float a, float b) {
#if __has_builtin(__builtin_amdgcn_cvt_pk_bf16_f32)
    typedef __attribute__((ext_vector_type(2))) __bf16 bf2;
    bf2 p = __builtin_amdgcn_cvt_pk_bf16_f32(a, b);
    return __builtin_bit_cast(unsigned int, p);
#else
    __bf16 x = (__bf16)a, y = (__bf16)b;   // clang lowers via HW cvt on gfx950
    return (unsigned int)__builtin_bit_cast(unsigned short, x) |
           ((unsigned int)__builtin_bit_cast(unsigned short, y) << 16);
#endif
}

__device__ inline f32x4 mfma16(bf16x8 a, bf16x8 b, f32x4 c) {
    return __builtin_amdgcn_mfma_f32_16x16x32_bf16(a, b, c, 0, 0, 0);
}

// ---------------------------------------------------------------------------
// prep: Wt[n][k] = W[k][n] bf16 (n: 0-63 K, 64-127 Q scaled, 128-191 V).
// Q scale folds 1/sqrt(512) AND log2(e): scores natively in log2 domain.
// Block 384 (only block touching fe): init fe[b]=T then end-token scan.
// ---------------------------------------------------------------------------
__global__ void prep_kernel(const float* __restrict__ Wk, const float* __restrict__ Wq,
                            const float* __restrict__ Wv, const int* __restrict__ idx,
                            unsigned short* __restrict__ Wt, int* __restrict__ fe) {
    if (blockIdx.x == 384) {
        if (threadIdx.x < B_) fe[threadIdx.x] = T_;
        __syncthreads();
#pragma unroll 4
        for (int i = threadIdx.x; i < B_ * T_; i += 256)
            if (idx[i] == 32000) atomicMin(&fe[i >> 11], i & 2047);
        return;
    }
    int id = blockIdx.x * 256 + threadIdx.x;     // [0, 3*32768)
    int mtx = id >> 15, rem = id & 32767;
    int k = rem >> 6, nl = rem & 63;
    const float* W = (mtx == 0) ? Wk : ((mtx == 1) ? Wq : Wv);
    float v = W[rem];                            // coalesced read
    if (mtx == 1) v *= 0.04419417382415922f * 1.4426950408889634f;  // /sqrt(512)*log2e
    Wt[(mtx * 64 + nl) * 512 + k] = f2bf(v);
}

// ---------------------------------------------------------------------------
// qkv: 32 tokens/block, 1024 blocks = 4/CU (32KB LDS, launch_bounds(256,4)).
// x-tile staged to LDS once (coalesced, packed cvt); wave w owns features
// 16w..16w+15 of K,Q,V; W-frags from L2-hot Wt. V computed transposed.
// ---------------------------------------------------------------------------
__global__ __launch_bounds__(256, 4) void qkv_kernel(
        const float* __restrict__ x, const unsigned short* __restrict__ Wt,
        unsigned short* __restrict__ Qm, unsigned short* __restrict__ Km,
        unsigned short* __restrict__ Vt) {
    __shared__ __align__(16) char smem[32768];
    unsigned short* xs = (unsigned short*)smem;  // [32][512] swizzled
    int tid = threadIdx.x, wave = tid >> 6, lane = tid & 63;
    int m16 = lane & 15, quad = lane >> 4;
    int row0 = blockIdx.x * 32;

#pragma unroll
    for (int i = 0; i < 8; i++) {                // stage x tile (coalesced)
        int u = tid + i * 256;                   // 2048 units of 8 floats
        int row = u >> 6, cu = u & 63;
        const f32x4* p = (const f32x4*)(x + (long)(row0 + row) * C_ + cu * 8);
        f32x4 a = p[0], bq = p[1];
        u32x4 t;
        t[0] = f2bf_pk(a[0], a[1]);  t[1] = f2bf_pk(a[2], a[3]);
        t[2] = f2bf_pk(bq[0], bq[1]); t[3] = f2bf_pk(bq[2], bq[3]);
        *(u32x4*)&xs[row * 512 + ((cu ^ (row & 7)) * 8)] = t;
    }
    __syncthreads();

    f32x4 ka[2], qa[2], va[2];
#pragma unroll
    for (int i = 0; i < 2; i++) {
        ka[i] = (f32x4){0.f, 0.f, 0.f, 0.f};
        qa[i] = (f32x4){0.f, 0.f, 0.f, 0.f};
        va[i] = (f32x4){0.f, 0.f, 0.f, 0.f};
    }
    int krw = (wave * 16 + m16) * 512;
    int qrw = krw + 64 * 512;
    int vrw = krw + 128 * 512;

#pragma unroll 2
    for (int cb = 0; cb < 8; cb++) {
#pragma unroll
        for (int half = 0; half < 2; half++) {
            int kk = cb * 64 + half * 32 + quad * 8;
            bf16x8 wk = *(const bf16x8*)&Wt[krw + kk];
            bf16x8 wq = *(const bf16x8*)&Wt[qrw + kk];
            bf16x8 wv = *(const bf16x8*)&Wt[vrw + kk];
            int g = kk >> 3;
            bf16x8 xf[2];
#pragma unroll
            for (int mt = 0; mt < 2; mt++) {
                int row = mt * 16 + m16;
                xf[mt] = *(const bf16x8*)&xs[row * 512 + ((g ^ (row & 7)) * 8)];
            }
#pragma unroll
            for (int mt = 0; mt < 2; mt++) ka[mt] = mfma16(xf[mt], wk, ka[mt]);
#pragma unroll
            for (int mt = 0; mt < 2; mt++) qa[mt] = mfma16(xf[mt], wq, qa[mt]);
#pragma unroll
            for (int mt = 0; mt < 2; mt++) va[mt] = mfma16(wv, xf[mt], va[mt]);  // V^T
        }
    }
    __syncthreads();                             // xs reads done -> reuse LDS

    unsigned short* co  = xs;                    // [32][136] K|Q
    unsigned short* vco = xs + 32 * 136;         // [4][16][40] V^T per wave
#pragma unroll
    for (int mt = 0; mt < 2; mt++) {
#pragma unroll
        for (int r = 0; r < 4; r++) {
            int trow = mt * 16 + quad * 4 + r;
            co[trow * 136 + wave * 16 + m16]      = f2bf(ka[mt][r]);
            co[trow * 136 + 64 + wave * 16 + m16] = f2bf(qa[mt][r]);
            vco[wave * 640 + (quad * 4 + r) * 40 + mt * 16 + m16] = f2bf(va[mt][r]);
        }
    }
    __syncthreads();
#pragma unroll
    for (int i = 0; i < 2; i++) {                // K/Q coalesced b128 stores
        int u = tid + i * 256; int tok = u >> 4; int fg = u & 15;
        bf16x8 vv = *(const bf16x8*)&co[tok * 136 + fg * 8];
        unsigned short* dst = (fg < 8) ? Km : Qm;
        *(bf16x8*)&dst[(long)(row0 + tok) * 64 + (fg & 7) * 8] = vv;
    }
    {                                            // V^T b128 stores
        int fl = lane >> 2, tg = lane & 3;
        bf16x8 vv = *(const bf16x8*)&vco[wave * 640 + fl * 40 + tg * 8];
        int bb = row0 >> 11, tl = row0 & 2047;
        *(bf16x8*)&Vt[((long)bb * 64 + wave * 16 + fl) * T_ + tl + tg * 8] = vv;
    }
}

// ---------------------------------------------------------------------------
// attn: S^T flash attention, split-K wave pairs (R4) + in-place K-prefetch
// (R3-proven) + packed P conversion. Grid (16,64); q-tiles paired {y,127-y}.
// ---------------------------------------------------------------------------
__global__ __launch_bounds__(256, 4) void attn_kernel(
        const unsigned short* __restrict__ Qm, const unsigned short* __restrict__ Km,
        const unsigned short* __restrict__ Vt, const int* __restrict__ fe,
        float* __restrict__ out) {
    __shared__ __align__(16) unsigned short Plds[4][16 * 64];
    __shared__ float MO[2][64 * 16];             // waveH=0 partial O^T [h][q]
    __shared__ float ML[2][2][16];               // waveH=0 partial m, l

    int b = blockIdx.x;                          // XCD = b%8 -> K/V L2-local
    int y = blockIdx.y;
    int tid = threadIdx.x, wave = tid >> 6, lane = tid & 63;
    int m16 = lane & 15, quad = lane >> 4;
    int pair = wave >> 1, waveH = wave & 1;
    int qt16 = pair ? y : (127 - y);             // paired big+small tiles
    int qrow0 = qt16 << 4;
    long bT = (long)b * T_;

    int nfull = qt16 >> 2;                       // diagonal tile index
    int ntiles = nfull + 1;
    int half = ntiles >> 1;
    int lo = waveH ? half : 0;
    int hi = waveH ? ntiles : half;

    const unsigned short* qp = Qm + (bT + qrow0 + m16) * 64;
    bf16x8 qf0 = *(const bf16x8*)(qp + quad * 8);        // B-frag of Q^T
    bf16x8 qf1 = *(const bf16x8*)(qp + 32 + quad * 8);

    const unsigned short* Kbase = Km + bT * 64;
    const unsigned short* Vbase = Vt + (long)b * 64 * T_;

    f32x4 o[5];
#pragma unroll
    for (int h = 0; h < 5; h++) o[h] = (f32x4){0.f, 0.f, 0.f, 0.f};
    float mi = -INFINITY;                        // per-lane: q = m16
    int q_abs = qrow0 + m16;

    bf16x8 onesa;                                // all-ones A-frag (denominator)
#pragma unroll
    for (int j = 0; j < 8; j++) onesa[j] = (short)0x3F80;

    unsigned short* pw = Plds[wave];
    int msw = (m16 & 7) * 8;                     // P xor-swizzle for this lane

    bf16x8 kf[8];                                // K A-frags (prefetched in-place)
#pragma unroll
    for (int ns = 0; ns < 4; ns++)
#pragma unroll
        for (int h = 0; h < 2; h++)
            kf[ns * 2 + h] = *(const bf16x8*)
                &Kbase[(lo * 64 + ns * 16 + m16) * 64 + h * 32 + quad * 8];

    for (int kt = lo; kt < hi; kt++) {
        bf16x8 vf[8];                            // V^T A-frags (early-issued)
#pragma unroll
        for (int hs = 0; hs < 4; hs++)
#pragma unroll
            for (int h = 0; h < 2; h++)
                vf[hs * 2 + h] = *(const bf16x8*)
                    &Vbase[(hs * 16 + m16) * T_ + kt * 64 + h * 32 + quad * 8];

        f32x4 s[4];                              // S^T: row=key, col=q=m16
#pragma unroll
        for (int ns = 0; ns < 4; ns++) {
            f32x4 z = (f32x4){0.f, 0.f, 0.f, 0.f};
            z = mfma16(kf[ns * 2], qf0, z);
            z = mfma16(kf[ns * 2 + 1], qf1, z);
            s[ns] = z;
        }

        if (kt + 1 < hi) {                       // prefetch next K tile in-place
#pragma unroll
            for (int ns = 0; ns < 4; ns++)
#pragma unroll
                for (int h = 0; h < 2; h++)
                    kf[ns * 2 + h] = *(const bf16x8*)
                        &Kbase[((kt + 1) * 64 + ns * 16 + m16) * 64 + h * 32 + quad * 8];
        }

        if (kt == nfull) {                       // causal mask on diagonal tile
#pragma unroll
            for (int ns = 0; ns < 4; ns++) {
                int kb = kt * 64 + ns * 16 + quad * 4;
#pragma unroll
                for (int r = 0; r < 4; r++)
                    if (kb + r > q_abs) s[ns][r] = -INFINITY;
            }
        }

        // per-lane softmax over 16 keys (scores in log2 domain)
        f32x4 t01, t;
#pragma unroll
        for (int r = 0; r < 4; r++) t01[r] = fmaxf(s[0][r], s[1][r]);
#pragma unroll
        for (int r = 0; r < 4; r++) t[r] = fmaxf(t01[r], fmaxf(s[2][r], s[3][r]));
        float mx = fmaxf(fmaxf(t[0], t[1]), fmaxf(t[2], t[3]));
        mx = fmaxf(mx, __shfl_xor(mx, 16));
        mx = fmaxf(mx, __shfl_xor(mx, 32));
        mx = fmaxf(mx, mi);
        float alpha = exp2f(mi - mx);
        mi = mx;
#pragma unroll
        for (int ns = 0; ns < 4; ns++)
#pragma unroll
            for (int r = 0; r < 4; r++) s[ns][r] = exp2f(s[ns][r] - mx);
#pragma unroll
        for (int h = 0; h < 5; h++) o[h] *= alpha;

        // P^T -> LDS [q=m16][key], packed cvt, xor-swizzled stride 64
#pragma unroll
        for (int ns = 0; ns < 4; ns++) {
            u32x2 pk;
            pk[0] = f2bf_pk(s[ns][0], s[ns][1]);
            pk[1] = f2bf_pk(s[ns][2], s[ns][3]);
            *(u32x2*)&pw[m16 * 64 + ((ns * 16 + quad * 4) ^ msw)] = pk;
        }
        bf16x8 pb0 = *(const bf16x8*)&pw[m16 * 64 + ((quad * 8) ^ msw)];
        bf16x8 pb1 = *(const bf16x8*)&pw[m16 * 64 + ((32 + quad * 8) ^ msw)];

#pragma unroll
        for (int hs = 0; hs < 4; hs++) {         // O^T += V^T P^T
            o[hs] = mfma16(vf[hs * 2], pb0, o[hs]);
            o[hs] = mfma16(vf[hs * 2 + 1], pb1, o[hs]);
        }
        o[4] = mfma16(onesa, pb0, o[4]);         // denominator (all lanes)
        o[4] = mfma16(onesa, pb1, o[4]);
    }

    if (!waveH) {                                // publish partial
#pragma unroll
        for (int hs = 0; hs < 4; hs++)
#pragma unroll
            for (int r = 0; r < 4; r++)
                MO[pair][(hs * 16 + quad * 4 + r) * 16 + m16] = o[hs][r];
        if (quad == 0) { ML[pair][0][m16] = mi; ML[pair][1][m16] = o[4][0]; }
    }
    __syncthreads();
    if (waveH) {                                 // merge + store
        float m0 = ML[pair][0][m16], l0 = ML[pair][1][m16];
        float M = fmaxf(m0, mi);
        float a0 = exp2f(m0 - M);
        float a1 = exp2f(mi - M);
        float l = a0 * l0 + a1 * o[4][0];
        float inv = 1.0f / l;
        int t = qrow0 + m16;
        bool dead = (t >= fe[b]);
#pragma unroll
        for (int hs = 0; hs < 4; hs++) {
            f32x4 res;
#pragma unroll
            for (int r = 0; r < 4; r++) {
                float v = (a1 * o[hs][r] + a0 * MO[pair][(hs * 16 + quad * 4 + r) * 16 + m16]) * inv;
                res[r] = dead ? __builtin_nanf("") : v;
            }
            *(f32x4*)&out[(bT + t) * 64 + hs * 16 + quad * 4] = res;
        }
    }
}

// ---------------------------------------------------------------------------
extern "C" void kernel_launch(void* const* d_in, const int* in_sizes, int n_in,
                              void* d_out, int out_size, void* d_ws, size_t ws_size,
                              hipStream_t stream) {
    const float* x  = (const float*)d_in[0];
    const float* Wk = (const float*)d_in[1];
    const float* Wq = (const float*)d_in[2];
    const float* Wv = (const float*)d_in[3];
    const int* idx  = (const int*)d_in[4];
    float* out = (float*)d_out;

    char* ws = (char*)d_ws;
    int* fe            = (int*)(ws + 64);                          //    64 B
    unsigned short* Wt = (unsigned short*)(ws + 1024);             //  192 KiB
    unsigned short* Qm = (unsigned short*)(ws + 262144);           //    4 MiB
    unsigned short* Km = (unsigned short*)(ws + 262144 + 4194304); //    4 MiB
    unsigned short* Vt = (unsigned short*)(ws + 262144 + 8388608); //    4 MiB

    prep_kernel<<<385, 256, 0, stream>>>(Wk, Wq, Wv, idx, Wt, fe);
    qkv_kernel<<<1024, 256, 0, stream>>>(x, Wt, Qm, Km, Vt);
    dim3 ga(16, 64);
    attn_kernel<<<ga, 256, 0, stream>>>(Qm, Km, Vt, fe, out);
}

// Round 7
// 191.013 us; speedup vs baseline: 2.3276x; 1.1696x over previous
//
#include <hip/hip_runtime.h>
#include <hip/hip_bf16.h>

// Head attention: B=16, T=2048, C=512(n_embd), H=64(head)
// out[b,t,h] = softmax_causal( (x@Wq)(x@Wk)^T * C^-0.5 ) @ (x@Wv)
// R7: attn = S^T split-K + TWO q-tiles per wave (K/V fragment traffic /2,
// the R6-diagnosed per-CU L2-miss-BW bound), K-prefetch reverted (R6 regression).
// qkv = R6 + one-step W-fragment register lookahead.

#define B_ 16
#define T_ 2048
#define C_ 512

typedef __attribute__((ext_vector_type(4))) float f32x4;
typedef __attribute__((ext_vector_type(8))) short bf16x8;
typedef __attribute__((ext_vector_type(4))) short bf16x4;
typedef __attribute__((ext_vector_type(4))) unsigned int u32x4;
typedef __attribute__((ext_vector_type(2))) unsigned int u32x2;

__device__ inline unsigned short f2bf(float f) {
    unsigned int u = __builtin_bit_cast(unsigned int, f);
    u += 0x7fff + ((u >> 16) & 1);   // RNE
    return (unsigned short)(u >> 16);
}

__device__ inline unsigned int f2bf_pk(float a, float b) {
#if __has_builtin(__builtin_amdgcn_cvt_pk_bf16_f32)
    typedef __attribute__((ext_vector_type(2))) __bf16 bf2;
    bf2 p = __builtin_amdgcn_cvt_pk_bf16_f32(a, b);
    return __builtin_bit_cast(unsigned int, p);
#else
    __bf16 x = (__bf16)a, y = (__bf16)b;
    return (unsigned int)__builtin_bit_cast(unsigned short, x) |
           ((unsigned int)__builtin_bit_cast(unsigned short, y) << 16);
#endif
}

__device__ inline f32x4 mfma16(bf16x8 a, bf16x8 b, f32x4 c) {
    return __builtin_amdgcn_mfma_f32_16x16x32_bf16(a, b, c, 0, 0, 0);
}

// ---------------------------------------------------------------------------
// prep: Wt[n][k] = W[k][n] bf16 (n: 0-63 K, 64-127 Q scaled, 128-191 V).
// Q scale folds 1/sqrt(512) AND log2(e). Block 384: fe init + end-token scan.
// ---------------------------------------------------------------------------
__global__ void prep_kernel(const float* __restrict__ Wk, const float* __restrict__ Wq,
                            const float* __restrict__ Wv, const int* __restrict__ idx,
                            unsigned short* __restrict__ Wt, int* __restrict__ fe) {
    if (blockIdx.x == 384) {
        if (threadIdx.x < B_) fe[threadIdx.x] = T_;
        __syncthreads();
#pragma unroll 4
        for (int i = threadIdx.x; i < B_ * T_; i += 256)
            if (idx[i] == 32000) atomicMin(&fe[i >> 11], i & 2047);
        return;
    }
    int id = blockIdx.x * 256 + threadIdx.x;
    int mtx = id >> 15, rem = id & 32767;
    int k = rem >> 6, nl = rem & 63;
    const float* W = (mtx == 0) ? Wk : ((mtx == 1) ? Wq : Wv);
    float v = W[rem];
    if (mtx == 1) v *= 0.04419417382415922f * 1.4426950408889634f;
    Wt[(mtx * 64 + nl) * 512 + k] = f2bf(v);
}

// ---------------------------------------------------------------------------
// qkv: 32 tokens/block, 1024 blocks (4/CU). x staged to LDS once; wave w owns
// features 16w..16w+15 of K,Q,V. Flat 16-step k-loop with one-step register
// lookahead on the W L2 loads. V computed transposed.
// ---------------------------------------------------------------------------
__global__ __launch_bounds__(256, 4) void qkv_kernel(
        const float* __restrict__ x, const unsigned short* __restrict__ Wt,
        unsigned short* __restrict__ Qm, unsigned short* __restrict__ Km,
        unsigned short* __restrict__ Vt) {
    __shared__ __align__(16) char smem[32768];
    unsigned short* xs = (unsigned short*)smem;  // [32][512] swizzled
    int tid = threadIdx.x, wave = tid >> 6, lane = tid & 63;
    int m16 = lane & 15, quad = lane >> 4;
    int row0 = blockIdx.x * 32;

#pragma unroll
    for (int i = 0; i < 8; i++) {                // stage x tile (coalesced)
        int u = tid + i * 256;
        int row = u >> 6, cu = u & 63;
        const f32x4* p = (const f32x4*)(x + (long)(row0 + row) * C_ + cu * 8);
        f32x4 a = p[0], bq = p[1];
        u32x4 t;
        t[0] = f2bf_pk(a[0], a[1]);  t[1] = f2bf_pk(a[2], a[3]);
        t[2] = f2bf_pk(bq[0], bq[1]); t[3] = f2bf_pk(bq[2], bq[3]);
        *(u32x4*)&xs[row * 512 + ((cu ^ (row & 7)) * 8)] = t;
    }
    __syncthreads();

    f32x4 ka[2], qa[2], va[2];
#pragma unroll
    for (int i = 0; i < 2; i++) {
        ka[i] = (f32x4){0.f, 0.f, 0.f, 0.f};
        qa[i] = (f32x4){0.f, 0.f, 0.f, 0.f};
        va[i] = (f32x4){0.f, 0.f, 0.f, 0.f};
    }
    int krw = (wave * 16 + m16) * 512;
    int qrw = krw + 64 * 512;
    int vrw = krw + 128 * 512;

    bf16x8 wkN = *(const bf16x8*)&Wt[krw + quad * 8];
    bf16x8 wqN = *(const bf16x8*)&Wt[qrw + quad * 8];
    bf16x8 wvN = *(const bf16x8*)&Wt[vrw + quad * 8];

#pragma unroll 4
    for (int st = 0; st < 16; st++) {            // 16 k-steps of 32
        bf16x8 wk = wkN, wq = wqN, wv = wvN;
        if (st < 15) {                           // lookahead next W frags (L2)
            int kk = (st + 1) * 32 + quad * 8;
            wkN = *(const bf16x8*)&Wt[krw + kk];
            wqN = *(const bf16x8*)&Wt[qrw + kk];
            wvN = *(const bf16x8*)&Wt[vrw + kk];
        }
        int kk = st * 32 + quad * 8;
        int g = kk >> 3;
        bf16x8 xf[2];
#pragma unroll
        for (int mt = 0; mt < 2; mt++) {
            int row = mt * 16 + m16;
            xf[mt] = *(const bf16x8*)&xs[row * 512 + ((g ^ (row & 7)) * 8)];
        }
#pragma unroll
        for (int mt = 0; mt < 2; mt++) ka[mt] = mfma16(xf[mt], wk, ka[mt]);
#pragma unroll
        for (int mt = 0; mt < 2; mt++) qa[mt] = mfma16(xf[mt], wq, qa[mt]);
#pragma unroll
        for (int mt = 0; mt < 2; mt++) va[mt] = mfma16(wv, xf[mt], va[mt]);  // V^T
    }
    __syncthreads();                             // xs reads done -> reuse LDS

    unsigned short* co  = xs;                    // [32][136] K|Q
    unsigned short* vco = xs + 32 * 136;         // [4][16][40] V^T per wave
#pragma unroll
    for (int mt = 0; mt < 2; mt++) {
#pragma unroll
        for (int r = 0; r < 4; r++) {
            int trow = mt * 16 + quad * 4 + r;
            co[trow * 136 + wave * 16 + m16]      = f2bf(ka[mt][r]);
            co[trow * 136 + 64 + wave * 16 + m16] = f2bf(qa[mt][r]);
            vco[wave * 640 + (quad * 4 + r) * 40 + mt * 16 + m16] = f2bf(va[mt][r]);
        }
    }
    __syncthreads();
#pragma unroll
    for (int i = 0; i < 2; i++) {                // K/Q coalesced b128 stores
        int u = tid + i * 256; int tok = u >> 4; int fg = u & 15;
        bf16x8 vv = *(const bf16x8*)&co[tok * 136 + fg * 8];
        unsigned short* dst = (fg < 8) ? Km : Qm;
        *(bf16x8*)&dst[(long)(row0 + tok) * 64 + (fg & 7) * 8] = vv;
    }
    {                                            // V^T b128 stores
        int fl = lane >> 2, tg = lane & 3;
        bf16x8 vv = *(const bf16x8*)&vco[wave * 640 + fl * 40 + tg * 8];
        int bb = row0 >> 11, tl = row0 & 2047;
        *(bf16x8*)&Vt[((long)bb * 64 + wave * 16 + fl) * T_ + tl + tg * 8] = vv;
    }
}

// ---------------------------------------------------------------------------
// attn: S^T flash attention, split-K wave pairs, TWO 16-row q-tiles per wave
// (shared K/V fragments halve L2 traffic). Grid (16,32); wave-unit u gets
// q-tiles {2u,2u+1}; block pairs u = {y, 63-y} for balance.
// ---------------------------------------------------------------------------
__global__ __launch_bounds__(256, 3) void attn_kernel(
        const unsigned short* __restrict__ Qm, const unsigned short* __restrict__ Km,
        const unsigned short* __restrict__ Vt, const int* __restrict__ fe,
        float* __restrict__ out) {
    __shared__ __align__(16) unsigned short Plds[4][2][16 * 64];
    __shared__ float MO[2][2][64 * 16];          // [pair][tile] partial O^T
    __shared__ float ML[2][2][2][16];            // [pair][tile][{m,l}]

    int b = blockIdx.x;                          // XCD = b%8 -> K/V L2-local
    int y = blockIdx.y;                          // [0,32)
    int tid = threadIdx.x, wave = tid >> 6, lane = tid & 63;
    int m16 = lane & 15, quad = lane >> 4;
    int pair = wave >> 1, waveH = wave & 1;
    int u = pair ? y : (63 - y);                 // wave-unit [0,64)
    int qrowA = (2 * u) << 4, qrowB = qrowA + 16;
    long bT = (long)b * T_;

    int nfull = (2 * u + 1) >> 2;                // shared diagonal tile index
    int ntiles = nfull + 1;
    int half = ntiles >> 1;
    int lo = waveH ? half : 0;
    int hi = waveH ? ntiles : half;

    const unsigned short* qpA = Qm + (bT + qrowA + m16) * 64;
    const unsigned short* qpB = Qm + (bT + qrowB + m16) * 64;
    bf16x8 qfA0 = *(const bf16x8*)(qpA + quad * 8);
    bf16x8 qfA1 = *(const bf16x8*)(qpA + 32 + quad * 8);
    bf16x8 qfB0 = *(const bf16x8*)(qpB + quad * 8);
    bf16x8 qfB1 = *(const bf16x8*)(qpB + 32 + quad * 8);

    const unsigned short* Kbase = Km + bT * 64;
    const unsigned short* Vbase = Vt + (long)b * 64 * T_;

    f32x4 oA[5], oB[5];
#pragma unroll
    for (int h = 0; h < 5; h++) {
        oA[h] = (f32x4){0.f, 0.f, 0.f, 0.f};
        oB[h] = (f32x4){0.f, 0.f, 0.f, 0.f};
    }
    float miA = -INFINITY, miB = -INFINITY;      // per-lane: q = m16
    int qA_abs = qrowA + m16, qB_abs = qrowB + m16;

    bf16x8 onesa;                                // all-ones A-frag (denominator)
#pragma unroll
    for (int j = 0; j < 8; j++) onesa[j] = (short)0x3F80;

    unsigned short* pwA = Plds[wave][0];
    unsigned short* pwB = Plds[wave][1];
    int msw = (m16 & 7) * 8;

    for (int kt = lo; kt < hi; kt++) {
        bf16x8 kf[8];                            // K A-frags (shared by A,B)
#pragma unroll
        for (int ns = 0; ns < 4; ns++)
#pragma unroll
            for (int h = 0; h < 2; h++)
                kf[ns * 2 + h] = *(const bf16x8*)
                    &Kbase[(kt * 64 + ns * 16 + m16) * 64 + h * 32 + quad * 8];

        f32x4 sA[4], sB[4];                      // S^T: row=key, col=q=m16
#pragma unroll
        for (int ns = 0; ns < 4; ns++) {
            f32x4 zA = (f32x4){0.f, 0.f, 0.f, 0.f};
            f32x4 zB = (f32x4){0.f, 0.f, 0.f, 0.f};
            zA = mfma16(kf[ns * 2], qfA0, zA);
            zB = mfma16(kf[ns * 2], qfB0, zB);
            zA = mfma16(kf[ns * 2 + 1], qfA1, zA);
            zB = mfma16(kf[ns * 2 + 1], qfB1, zB);
            sA[ns] = zA; sB[ns] = zB;
        }

        bf16x8 vf[8];                            // V^T A-frags (shared by A,B)
#pragma unroll
        for (int hs = 0; hs < 4; hs++)
#pragma unroll
            for (int h = 0; h < 2; h++)
                vf[hs * 2 + h] = *(const bf16x8*)
                    &Vbase[(hs * 16 + m16) * T_ + kt * 64 + h * 32 + quad * 8];

        if (kt == nfull) {                       // causal mask, both tiles
#pragma unroll
            for (int ns = 0; ns < 4; ns++) {
                int kb = kt * 64 + ns * 16 + quad * 4;
#pragma unroll
                for (int r = 0; r < 4; r++) {
                    if (kb + r > qA_abs) sA[ns][r] = -INFINITY;
                    if (kb + r > qB_abs) sB[ns][r] = -INFINITY;
                }
            }
        }

        // --- softmax tile A (log2 domain)
        {
            f32x4 t;
#pragma unroll
            for (int r = 0; r < 4; r++)
                t[r] = fmaxf(fmaxf(sA[0][r], sA[1][r]), fmaxf(sA[2][r], sA[3][r]));
            float mx = fmaxf(fmaxf(t[0], t[1]), fmaxf(t[2], t[3]));
            mx = fmaxf(mx, __shfl_xor(mx, 16));
            mx = fmaxf(mx, __shfl_xor(mx, 32));
            mx = fmaxf(mx, miA);
            float alpha = exp2f(miA - mx);
            miA = mx;
#pragma unroll
            for (int ns = 0; ns < 4; ns++)
#pragma unroll
                for (int r = 0; r < 4; r++) sA[ns][r] = exp2f(sA[ns][r] - mx);
#pragma unroll
            for (int h = 0; h < 5; h++) oA[h] *= alpha;
        }
        // --- softmax tile B
        {
            f32x4 t;
#pragma unroll
            for (int r = 0; r < 4; r++)
                t[r] = fmaxf(fmaxf(sB[0][r], sB[1][r]), fmaxf(sB[2][r], sB[3][r]));
            float mx = fmaxf(fmaxf(t[0], t[1]), fmaxf(t[2], t[3]));
            mx = fmaxf(mx, __shfl_xor(mx, 16));
            mx = fmaxf(mx, __shfl_xor(mx, 32));
            mx = fmaxf(mx, miB);
            float alpha = exp2f(miB - mx);
            miB = mx;
#pragma unroll
            for (int ns = 0; ns < 4; ns++)
#pragma unroll
                for (int r = 0; r < 4; r++) sB[ns][r] = exp2f(sB[ns][r] - mx);
#pragma unroll
            for (int h = 0; h < 5; h++) oB[h] *= alpha;
        }

        // --- P^T -> LDS, packed cvt, xor-swizzled
#pragma unroll
        for (int ns = 0; ns < 4; ns++) {
            u32x2 pkA, pkB;
            pkA[0] = f2bf_pk(sA[ns][0], sA[ns][1]);
            pkA[1] = f2bf_pk(sA[ns][2], sA[ns][3]);
            pkB[0] = f2bf_pk(sB[ns][0], sB[ns][1]);
            pkB[1] = f2bf_pk(sB[ns][2], sB[ns][3]);
            int off = m16 * 64 + ((ns * 16 + quad * 4) ^ msw);
            *(u32x2*)&pwA[off] = pkA;
            *(u32x2*)&pwB[off] = pkB;
        }
        bf16x8 pbA0 = *(const bf16x8*)&pwA[m16 * 64 + ((quad * 8) ^ msw)];
        bf16x8 pbA1 = *(const bf16x8*)&pwA[m16 * 64 + ((32 + quad * 8) ^ msw)];
        bf16x8 pbB0 = *(const bf16x8*)&pwB[m16 * 64 + ((quad * 8) ^ msw)];
        bf16x8 pbB1 = *(const bf16x8*)&pwB[m16 * 64 + ((32 + quad * 8) ^ msw)];

#pragma unroll
        for (int hs = 0; hs < 4; hs++) {         // O^T += V^T P^T, both tiles
            oA[hs] = mfma16(vf[hs * 2], pbA0, oA[hs]);
            oB[hs] = mfma16(vf[hs * 2], pbB0, oB[hs]);
            oA[hs] = mfma16(vf[hs * 2 + 1], pbA1, oA[hs]);
            oB[hs] = mfma16(vf[hs * 2 + 1], pbB1, oB[hs]);
        }
        oA[4] = mfma16(onesa, pbA0, oA[4]);
        oA[4] = mfma16(onesa, pbA1, oA[4]);
        oB[4] = mfma16(onesa, pbB0, oB[4]);
        oB[4] = mfma16(onesa, pbB1, oB[4]);
    }

    if (!waveH) {                                // publish partials
#pragma unroll
        for (int hs = 0; hs < 4; hs++)
#pragma unroll
            for (int r = 0; r < 4; r++) {
                MO[pair][0][(hs * 16 + quad * 4 + r) * 16 + m16] = oA[hs][r];
                MO[pair][1][(hs * 16 + quad * 4 + r) * 16 + m16] = oB[hs][r];
            }
        if (quad == 0) {
            ML[pair][0][0][m16] = miA; ML[pair][0][1][m16] = oA[4][0];
            ML[pair][1][0][m16] = miB; ML[pair][1][1][m16] = oB[4][0];
        }
    }
    __syncthreads();
    if (waveH) {                                 // merge + store, both tiles
        int feb = fe[b];
#pragma unroll
        for (int tile = 0; tile < 2; tile++) {
            float mi = tile ? miB : miA;
            float m0 = ML[pair][tile][0][m16], l0 = ML[pair][tile][1][m16];
            float M = fmaxf(m0, mi);
            float a0 = exp2f(m0 - M);
            float a1 = exp2f(mi - M);
            float lown = tile ? oB[4][0] : oA[4][0];
            float l = a0 * l0 + a1 * lown;
            float inv = 1.0f / l;
            int t = (tile ? qrowB : qrowA) + m16;
            bool dead = (t >= feb);
#pragma unroll
            for (int hs = 0; hs < 4; hs++) {
                f32x4 res;
#pragma unroll
                for (int r = 0; r < 4; r++) {
                    float own = tile ? oB[hs][r] : oA[hs][r];
                    float v = (a1 * own +
                               a0 * MO[pair][tile][(hs * 16 + quad * 4 + r) * 16 + m16]) * inv;
                    res[r] = dead ? __builtin_nanf("") : v;
                }
                *(f32x4*)&out[(bT + t) * 64 + hs * 16 + quad * 4] = res;
            }
        }
    }
}

// ---------------------------------------------------------------------------
extern "C" void kernel_launch(void* const* d_in, const int* in_sizes, int n_in,
                              void* d_out, int out_size, void* d_ws, size_t ws_size,
                              hipStream_t stream) {
    const float* x  = (const float*)d_in[0];
    const float* Wk = (const float*)d_in[1];
    const float* Wq = (const float*)d_in[2];
    const float* Wv = (const float*)d_in[3];
    const int* idx  = (const int*)d_in[4];
    float* out = (float*)d_out;

    char* ws = (char*)d_ws;
    int* fe            = (int*)(ws + 64);                          //    64 B
    unsigned short* Wt = (unsigned short*)(ws + 1024);             //  192 KiB
    unsigned short* Qm = (unsigned short*)(ws + 262144);           //    4 MiB
    unsigned short* Km = (unsigned short*)(ws + 262144 + 4194304); //    4 MiB
    unsigned short* Vt = (unsigned short*)(ws + 262144 + 8388608); //    4 MiB

    prep_kernel<<<385, 256, 0, stream>>>(Wk, Wq, Wv, idx, Wt, fe);
    qkv_kernel<<<1024, 256, 0, stream>>>(x, Wt, Qm, Km, Vt);
    dim3 ga(16, 32);
    attn_kernel<<<ga, 256, 0, stream>>>(Qm, Km, Vt, fe, out);
}